// Round 1
// baseline (1552.322 us; speedup 1.0000x reference)
//
#include <hip/hip_runtime.h>

#define LRELU(x) ((x) > 0.f ? (x) : 0.2f * (x))

// ---------------- small helpers ----------------

__global__ void zero_ints_k(int* __restrict__ a, int* __restrict__ b, int n) {
  int i = blockIdx.x * 256 + threadIdx.x;
  if (i < n) { a[i] = 0; b[i] = 0; }
}

// sw[0..2] = We1^T @ ae1 per edge-dim row; sw[3] = We2 . ae2; sw[4] = We3 . ae3
__global__ void small_weights_k(const float* __restrict__ We1, const float* __restrict__ ae1,
                                const float* __restrict__ We2, const float* __restrict__ ae2,
                                const float* __restrict__ We3, const float* __restrict__ ae3,
                                float* __restrict__ sw) {
  int t = threadIdx.x;  // 64 threads = 1 wave
  float v0 = We1[t] * ae1[t];
  float v1 = We1[64 + t] * ae1[t];
  float v2 = We1[128 + t] * ae1[t];
  float v3 = We2[t] * ae2[t];
  float v4 = (t < 32) ? We3[t] * ae3[t] : 0.f;
#pragma unroll
  for (int off = 32; off > 0; off >>= 1) {
    v0 += __shfl_down(v0, off);
    v1 += __shfl_down(v1, off);
    v2 += __shfl_down(v2, off);
    v3 += __shfl_down(v3, off);
    v4 += __shfl_down(v4, off);
  }
  if (t == 0) { sw[0] = v0; sw[1] = v1; sw[2] = v2; sw[3] = v3; sw[4] = v4; }
}

__global__ void count_deg_k(const int* __restrict__ dst, int* __restrict__ deg, int E) {
  int i = blockIdx.x * 256 + threadIdx.x;
  if (i < E) atomicAdd(&deg[dst[i]], 1);
}

// ---------------- exclusive scan (rowptr) ----------------

__global__ void scan1_k(const int* __restrict__ deg, int* __restrict__ rowptr,
                        int* __restrict__ bsum, int n) {
  __shared__ int s[1024];
  int t = threadIdx.x, i = blockIdx.x * 1024 + t;
  int v = (i < n) ? deg[i] : 0;
  s[t] = v;
  __syncthreads();
  for (int off = 1; off < 1024; off <<= 1) {
    int add = (t >= off) ? s[t - off] : 0;
    __syncthreads();
    s[t] += add;
    __syncthreads();
  }
  if (i < n) rowptr[i + 1] = s[t];
  if (t == 1023) bsum[blockIdx.x] = s[t];
}

__global__ void scan2_k(const int* __restrict__ bsum, int* __restrict__ boff, int nb) {
  if (threadIdx.x == 0) {
    int acc = 0;
    for (int b = 0; b < nb; b++) { boff[b] = acc; acc += bsum[b]; }
  }
}

__global__ void scan3_k(int* __restrict__ rowptr, const int* __restrict__ boff, int n) {
  int i = blockIdx.x * 256 + threadIdx.x;
  if (i < n) rowptr[i + 1] += boff[i / 1024];
  if (i == 0) rowptr[0] = 0;
}

// ---------------- CSR scatter (also folds edge_attr @ We1 @ ae1 into a scalar) --------

__global__ void scatter_k(const int* __restrict__ src, const int* __restrict__ dst,
                          const float* __restrict__ eattr, const int* __restrict__ rowptr,
                          int* __restrict__ fill, int* __restrict__ src_csr,
                          float* __restrict__ attr, const float* __restrict__ sw, int E) {
  int e = blockIdx.x * 256 + threadIdx.x;
  if (e >= E) return;
  int d = dst[e];
  int pos = rowptr[d] + atomicAdd(&fill[d], 1);
  src_csr[pos] = src[e];
  attr[pos] = eattr[e * 3] * sw[0] + eattr[e * 3 + 1] * sw[1] + eattr[e * 3 + 2] * sw[2];
}

// ---------------- GEMMs (wave per node, lane = out channel) ----------------

// layer 1: x [n,5] @ W [5,64], fused asrc/adst projections
__global__ void gemm1_k(const float* __restrict__ x, const float* __restrict__ W,
                        const float* __restrict__ as, const float* __restrict__ ad,
                        float* __restrict__ h, float* __restrict__ asrc,
                        float* __restrict__ adst, int n) {
  int lane = threadIdx.x & 63;
  int v = (blockIdx.x * blockDim.x + threadIdx.x) >> 6;
  if (v >= n) return;
  float acc = 0.f;
#pragma unroll
  for (int k = 0; k < 5; k++) acc += x[v * 5 + k] * W[k * 64 + lane];
  h[v * 64 + lane] = acc;
  float ps = acc * as[lane], pd = acc * ad[lane];
#pragma unroll
  for (int off = 32; off > 0; off >>= 1) {
    ps += __shfl_down(ps, off);
    pd += __shfl_down(pd, off);
  }
  if (lane == 0) { asrc[v] = ps; adst[v] = pd; }
}

// layers 2/3: x [n,64] @ W [64,C], C in {64,32}
template <int C>
__global__ void gemm64_k(const float* __restrict__ x, const float* __restrict__ W,
                         const float* __restrict__ as, const float* __restrict__ ad,
                         float* __restrict__ h, float* __restrict__ asrc,
                         float* __restrict__ adst, int n) {
  __shared__ float Wl[64 * C];
  int t = threadIdx.x;
  for (int i = t; i < 64 * C; i += blockDim.x) Wl[i] = W[i];
  __syncthreads();
  int lane = t & 63;
  int v = (blockIdx.x * blockDim.x + t) >> 6;
  if (v >= n) return;
  float xr = x[v * 64 + lane];
  if (C == 64) {
    float acc = 0.f;
#pragma unroll 16
    for (int k = 0; k < 64; k++) acc += __shfl(xr, k) * Wl[k * 64 + lane];
    h[v * 64 + lane] = acc;
    float ps = acc * as[lane], pd = acc * ad[lane];
#pragma unroll
    for (int off = 32; off > 0; off >>= 1) {
      ps += __shfl_down(ps, off);
      pd += __shfl_down(pd, off);
    }
    if (lane == 0) { asrc[v] = ps; adst[v] = pd; }
  } else {  // C == 32: k-split across half-waves, combine via xor(32)
    int c = lane & 31;
    float p = 0.f;
#pragma unroll 8
    for (int kk = 0; kk < 32; kk++) {
      int k = (lane & 32) + kk;
      p += __shfl(xr, k) * Wl[k * C + c];
    }
    p += __shfl_xor(p, 32);
    if (lane < 32) {
      h[v * 32 + c] = p;
      float ps = p * as[c], pd = p * ad[c];
#pragma unroll
      for (int off = 16; off > 0; off >>= 1) {
        ps += __shfl_down(ps, off);
        pd += __shfl_down(pd, off);
      }
      if (lane == 0) { asrc[v] = ps; adst[v] = pd; }
    }
  }
}

// ---------------- per-node softmax + aggregate (wave per node) ----------------
// LAYER=1: attr holds precomputed ae per edge, s=1, no prior loops.
// LAYER=2: attr holds alpha1; prior loop lp1 (layer-1 self loop alpha).
// LAYER=3: attr holds alpha2; prior loops lp1, lp2. No alpha outputs needed.
template <int LAYER, int C>
__global__ void agg_k(const int* __restrict__ rowptr, const int* __restrict__ src_csr,
                      const float* __restrict__ h, const float* __restrict__ asrc,
                      const float* __restrict__ adst, float* __restrict__ attr,
                      const float* __restrict__ lp1, const float* __restrict__ lp2,
                      float* __restrict__ ol1, float* __restrict__ ol2,
                      const float* __restrict__ sw, const float* __restrict__ bias,
                      float* __restrict__ out, int n) {
  int lane = threadIdx.x & 63;
  int v = (blockIdx.x * blockDim.x + threadIdx.x) >> 6;
  if (v >= n) return;
  const float s = (LAYER == 1) ? 1.f : (LAYER == 2 ? sw[3] : sw[4]);
  int r0 = rowptr[v], r1 = rowptr[v + 1];
  int deg = r1 - r0;
  float av_s = asrc[v], av_d = adst[v];

  // phase 1: max logit + attr sum (lane-parallel over CSR edges)
  float mx = -1e30f, asum = 0.f;
  for (int p = r0 + lane; p < r1; p += 64) {
    float a = attr[p];
    float lg = asrc[src_csr[p]] + av_d + s * a;
    lg = LRELU(lg);
    mx = fmaxf(mx, lg);
    asum += a;
  }
#pragma unroll
  for (int off = 32; off > 0; off >>= 1) {
    mx = fmaxf(mx, __shfl_xor(mx, off));
    asum += __shfl_xor(asum, off);
  }

  float la1 = 0.f, la2 = 0.f;
  if (LAYER >= 2) { la1 = lp1[v]; asum += la1; }
  if (LAYER >= 3) { la2 = lp2[v]; asum += la2; }
  int dd = deg + (LAYER - 1);
  if (dd < 1) dd = 1;
  float lmean = asum / (float)dd;
  float base = av_s + av_d;
  float lg1 = 0.f, lg2 = 0.f;
  if (LAYER >= 2) { lg1 = LRELU(base + s * la1); mx = fmaxf(mx, lg1); }
  if (LAYER >= 3) { lg2 = LRELU(base + s * la2); mx = fmaxf(mx, lg2); }
  float lgm = LRELU(base + s * lmean);
  mx = fmaxf(mx, lgm);

  // phase 2: per-edge exp + channel accumulate (lane = channel; edges sequential)
  int c = (C == 64) ? lane : (lane & 31);
  float acc = 0.f, denom = 0.f;
  for (int p = r0; p < r1; ++p) {
    int sv = src_csr[p];
    float a = attr[p];
    float lg = asrc[sv] + av_d + s * a;
    lg = LRELU(lg);
    float ex = __expf(lg - mx);
    denom += ex;
    acc += ex * h[sv * C + c];
  }
  float hv = h[v * C + c];
  float e1 = 0.f;
  if (LAYER >= 2) { e1 = __expf(lg1 - mx); denom += e1; acc += e1 * hv; }
  if (LAYER >= 3) { float e2 = __expf(lg2 - mx); denom += e2; acc += e2 * hv; }
  float exm = __expf(lgm - mx);
  denom += exm;
  acc += exm * hv;
  float inv = 1.f / (denom + 1e-16f);

  if (lane == 0) {
    if (LAYER == 1) ol1[v] = exm * inv;
    if (LAYER == 2) { ol1[v] = e1 * inv; ol2[v] = exm * inv; }
  }

  // phase 3: write normalized alphas back in CSR order (input to next layer)
  if (LAYER < 3) {
    for (int p = r0 + lane; p < r1; p += 64) {
      float a = attr[p];
      float lg = asrc[src_csr[p]] + av_d + s * a;
      lg = LRELU(lg);
      attr[p] = __expf(lg - mx) * inv;
    }
  }

  // output
  float o = acc * inv + bias[c];
  if (LAYER < 3) o = fmaxf(o, 0.f);
  if (C == 64) out[v * 64 + lane] = o;
  else if (lane < 32) out[v * 32 + c] = o;
}

// ---------------- global mean pool (block per graph) ----------------

__global__ void pool_k(const float* __restrict__ h, const int* __restrict__ batch,
                       float* __restrict__ out, int n) {
  int g = blockIdx.x;
  // lower_bound(batch, g) and lower_bound(batch, g+1)
  int lo = 0, hi = n;
  while (lo < hi) { int m = (lo + hi) >> 1; if (batch[m] < g) lo = m + 1; else hi = m; }
  int start = lo;
  hi = n;
  while (lo < hi) { int m = (lo + hi) >> 1; if (batch[m] < g + 1) lo = m + 1; else hi = m; }
  int end = lo;
  int t = threadIdx.x;        // 256 threads
  int c = t & 31, r = t >> 5; // 8 node-rows in flight
  float acc = 0.f;
  for (int v = start + r; v < end; v += 8) acc += h[v * 32 + c];
  __shared__ float s[256];
  s[t] = acc;
  __syncthreads();
  if (t < 128) s[t] += s[t + 128];
  __syncthreads();
  if (t < 64) s[t] += s[t + 64];
  __syncthreads();
  if (t < 32) {
    float tot = s[t] + s[t + 32];
    int cnt = end - start;
    out[g * 32 + t] = tot / (float)(cnt > 0 ? cnt : 1);
  }
}

// ---------------- launch ----------------

extern "C" void kernel_launch(void* const* d_in, const int* in_sizes, int n_in,
                              void* d_out, int out_size, void* d_ws, size_t ws_size,
                              hipStream_t stream) {
  const float* x     = (const float*)d_in[0];
  const int*   ei    = (const int*)d_in[1];
  const float* eattr = (const float*)d_in[2];
  const int*   batch = (const int*)d_in[3];
  const float *W1 = (const float*)d_in[4],  *as1 = (const float*)d_in[5],
              *ad1 = (const float*)d_in[6], *We1 = (const float*)d_in[7],
              *ae1 = (const float*)d_in[8], *b1  = (const float*)d_in[9];
  const float *W2 = (const float*)d_in[10], *as2 = (const float*)d_in[11],
              *ad2 = (const float*)d_in[12], *We2 = (const float*)d_in[13],
              *ae2 = (const float*)d_in[14], *b2  = (const float*)d_in[15];
  const float *W3 = (const float*)d_in[16], *as3 = (const float*)d_in[17],
              *ad3 = (const float*)d_in[18], *We3 = (const float*)d_in[19],
              *ae3 = (const float*)d_in[20], *b3  = (const float*)d_in[21];

  const int n = in_sizes[3];      // N nodes
  const int E = in_sizes[1] / 2;  // edges
  const int G = out_size / 32;    // graphs
  const int* srcp = ei;
  const int* dstp = ei + E;

  // bump allocator over d_ws
  char* w = (char*)d_ws;
  auto alloc = [&](size_t bytes) -> void* {
    void* p = (void*)w;
    w += (bytes + 255) & ~(size_t)255;
    return p;
  };
  int*   deg     = (int*)alloc((size_t)n * 4);
  int*   fill    = (int*)alloc((size_t)n * 4);
  int*   rowptr  = (int*)alloc((size_t)(n + 1) * 4);
  int*   bsum    = (int*)alloc(1024);
  int*   boff    = (int*)alloc(1024);
  int*   src_csr = (int*)alloc((size_t)E * 4);
  float* attr    = (float*)alloc((size_t)E * 4);
  float* H       = (float*)alloc((size_t)n * 64 * 4);
  float* O       = (float*)alloc((size_t)n * 64 * 4);
  float* asrcB   = (float*)alloc((size_t)n * 4);
  float* adstB   = (float*)alloc((size_t)n * 4);
  float* loopA   = (float*)alloc((size_t)n * 4);
  float* loopB1  = (float*)alloc((size_t)n * 4);
  float* loopB2  = (float*)alloc((size_t)n * 4);
  float* sw      = (float*)alloc(256);

  const int nb = (n + 1023) / 1024;
  dim3 blk256(256);
  dim3 gN((n + 255) / 256);
  dim3 gE((E + 255) / 256);
  dim3 gWave((n + 3) / 4);  // 4 waves per 256-thread block, wave per node

  zero_ints_k<<<gN, blk256, 0, stream>>>(deg, fill, n);
  small_weights_k<<<1, 64, 0, stream>>>(We1, ae1, We2, ae2, We3, ae3, sw);
  count_deg_k<<<gE, blk256, 0, stream>>>(dstp, deg, E);
  scan1_k<<<nb, 1024, 0, stream>>>(deg, rowptr, bsum, n);
  scan2_k<<<1, 64, 0, stream>>>(bsum, boff, nb);
  scan3_k<<<gN, blk256, 0, stream>>>(rowptr, boff, n);
  scatter_k<<<gE, blk256, 0, stream>>>(srcp, dstp, eattr, rowptr, fill, src_csr, attr, sw, E);

  // layer 1
  gemm1_k<<<gWave, blk256, 0, stream>>>(x, W1, as1, ad1, H, asrcB, adstB, n);
  agg_k<1, 64><<<gWave, blk256, 0, stream>>>(rowptr, src_csr, H, asrcB, adstB, attr,
                                             nullptr, nullptr, loopA, nullptr, sw, b1, O, n);
  // layer 2
  gemm64_k<64><<<gWave, blk256, 0, stream>>>(O, W2, as2, ad2, H, asrcB, adstB, n);
  agg_k<2, 64><<<gWave, blk256, 0, stream>>>(rowptr, src_csr, H, asrcB, adstB, attr,
                                             loopA, nullptr, loopB1, loopB2, sw, b2, O, n);
  // layer 3
  gemm64_k<32><<<gWave, blk256, 0, stream>>>(O, W3, as3, ad3, H, asrcB, adstB, n);
  agg_k<3, 32><<<gWave, blk256, 0, stream>>>(rowptr, src_csr, H, asrcB, adstB, attr,
                                             loopB1, loopB2, nullptr, nullptr, sw, b3, O, n);
  // pool
  pool_k<<<G, blk256, 0, stream>>>(O, batch, (float*)d_out, n);
}

// Round 2
// 843.579 us; speedup vs baseline: 1.8402x; 1.8402x over previous
//
#include <hip/hip_runtime.h>

#define LRELU(x) ((x) > 0.f ? (x) : 0.2f * (x))

// ---------------- small helpers ----------------

__global__ void zero_ints_k(int* __restrict__ a, int* __restrict__ b, int n) {
  int i = blockIdx.x * 256 + threadIdx.x;
  if (i < n) { a[i] = 0; b[i] = 0; }
}

// sw[0..2] = We1^T @ ae1 per edge-dim row; sw[3] = We2 . ae2; sw[4] = We3 . ae3
__global__ void small_weights_k(const float* __restrict__ We1, const float* __restrict__ ae1,
                                const float* __restrict__ We2, const float* __restrict__ ae2,
                                const float* __restrict__ We3, const float* __restrict__ ae3,
                                float* __restrict__ sw) {
  int t = threadIdx.x;  // 64 threads = 1 wave
  float v0 = We1[t] * ae1[t];
  float v1 = We1[64 + t] * ae1[t];
  float v2 = We1[128 + t] * ae1[t];
  float v3 = We2[t] * ae2[t];
  float v4 = (t < 32) ? We3[t] * ae3[t] : 0.f;
#pragma unroll
  for (int off = 32; off > 0; off >>= 1) {
    v0 += __shfl_down(v0, off);
    v1 += __shfl_down(v1, off);
    v2 += __shfl_down(v2, off);
    v3 += __shfl_down(v3, off);
    v4 += __shfl_down(v4, off);
  }
  if (t == 0) { sw[0] = v0; sw[1] = v1; sw[2] = v2; sw[3] = v3; sw[4] = v4; }
}

__global__ void count_deg_k(const int* __restrict__ dst, int* __restrict__ deg, int E) {
  int i = blockIdx.x * 256 + threadIdx.x;
  if (i < E) atomicAdd(&deg[dst[i]], 1);
}

// ---------------- exclusive scan (rowptr) ----------------

__global__ void scan1_k(const int* __restrict__ deg, int* __restrict__ rowptr,
                        int* __restrict__ bsum, int n) {
  __shared__ int s[1024];
  int t = threadIdx.x, i = blockIdx.x * 1024 + t;
  int v = (i < n) ? deg[i] : 0;
  s[t] = v;
  __syncthreads();
  for (int off = 1; off < 1024; off <<= 1) {
    int add = (t >= off) ? s[t - off] : 0;
    __syncthreads();
    s[t] += add;
    __syncthreads();
  }
  if (i < n) rowptr[i + 1] = s[t];
  if (t == 1023) bsum[blockIdx.x] = s[t];
}

__global__ void scan2_k(const int* __restrict__ bsum, int* __restrict__ boff, int nb) {
  if (threadIdx.x == 0) {
    int acc = 0;
    for (int b = 0; b < nb; b++) { boff[b] = acc; acc += bsum[b]; }
  }
}

__global__ void scan3_k(int* __restrict__ rowptr, const int* __restrict__ boff, int n) {
  int i = blockIdx.x * 256 + threadIdx.x;
  if (i < n) rowptr[i + 1] += boff[i / 1024];
  if (i == 0) rowptr[0] = 0;
}

// ---------------- CSR scatter (folds edge_attr @ We1 @ ae1 into a scalar) --------

__global__ void scatter_k(const int* __restrict__ src, const int* __restrict__ dst,
                          const float* __restrict__ eattr, const int* __restrict__ rowptr,
                          int* __restrict__ fill, int* __restrict__ src_csr,
                          float* __restrict__ attr, const float* __restrict__ sw, int E) {
  int e = blockIdx.x * 256 + threadIdx.x;
  if (e >= E) return;
  int d = dst[e];
  int pos = rowptr[d] + atomicAdd(&fill[d], 1);
  src_csr[pos] = src[e];
  attr[pos] = eattr[e * 3] * sw[0] + eattr[e * 3 + 1] * sw[1] + eattr[e * 3 + 2] * sw[2];
}

// ---------------- layer-1 GEMM: x [n,5] @ W [5,64] (wave per node) -------------

__global__ void gemm1_k(const float* __restrict__ x, const float* __restrict__ W,
                        const float* __restrict__ as, const float* __restrict__ ad,
                        float* __restrict__ h, float* __restrict__ asrc,
                        float* __restrict__ adst, int n) {
  int lane = threadIdx.x & 63;
  int v = (blockIdx.x * blockDim.x + threadIdx.x) >> 6;
  if (v >= n) return;
  float acc = 0.f;
#pragma unroll
  for (int k = 0; k < 5; k++) acc += x[v * 5 + k] * W[k * 64 + lane];
  h[(size_t)v * 64 + lane] = acc;
  float ps = acc * as[lane], pd = acc * ad[lane];
#pragma unroll
  for (int off = 32; off > 0; off >>= 1) {
    ps += __shfl_down(ps, off);
    pd += __shfl_down(pd, off);
  }
  if (lane == 0) { asrc[v] = ps; adst[v] = pd; }
}

// ---------------- tiled GEMM: x [n,64] @ W [64,C], 4x4 register blocking -------

template <int C>
__global__ __launch_bounds__(256) void gemm_tile_k(
    const float* __restrict__ x, const float* __restrict__ W,
    const float* __restrict__ as, const float* __restrict__ ad,
    float* __restrict__ h, float* __restrict__ asrc, float* __restrict__ adst, int n) {
  constexpr int NT = 4096 / C;   // nodes per block: 64 (C=64) / 128 (C=32)
  constexpr int CG = C / 4;      // channel groups: 16 / 8
  constexpr int XTP = NT + 4;    // pad keeps float4 alignment
  __shared__ float XT[64][XTP];  // transposed x tile: XT[k][node]
  __shared__ float Wl[64 * C];
  const int t = threadIdx.x;
  const int v0 = blockIdx.x * NT;
  for (int i = t; i < 64 * C; i += 256) Wl[i] = W[i];
  for (int i = t; i < NT * 64; i += 256) {
    int node = i >> 6, k = i & 63;
    int v = v0 + node;
    XT[k][node] = (v < n) ? x[(size_t)v * 64 + k] : 0.f;
  }
  __syncthreads();
  const int cg = t % CG, ng = t / CG;
  const int c0 = cg * 4, n0 = ng * 4;
  float acc[4][4] = {};
#pragma unroll 4
  for (int k = 0; k < 64; ++k) {
    const float4 xv = *(const float4*)&XT[k][n0];
    const float4 wv = *(const float4*)&Wl[k * C + c0];
    acc[0][0] += xv.x * wv.x; acc[0][1] += xv.x * wv.y; acc[0][2] += xv.x * wv.z; acc[0][3] += xv.x * wv.w;
    acc[1][0] += xv.y * wv.x; acc[1][1] += xv.y * wv.y; acc[1][2] += xv.y * wv.z; acc[1][3] += xv.y * wv.w;
    acc[2][0] += xv.z * wv.x; acc[2][1] += xv.z * wv.y; acc[2][2] += xv.z * wv.z; acc[2][3] += xv.z * wv.w;
    acc[3][0] += xv.w * wv.x; acc[3][1] += xv.w * wv.y; acc[3][2] += xv.w * wv.z; acc[3][3] += xv.w * wv.w;
  }
  float asv[4] = {as[c0], as[c0 + 1], as[c0 + 2], as[c0 + 3]};
  float adv[4] = {ad[c0], ad[c0 + 1], ad[c0 + 2], ad[c0 + 3]};
  float ps[4], pd[4];
#pragma unroll
  for (int ni = 0; ni < 4; ++ni) {
    ps[ni] = acc[ni][0] * asv[0] + acc[ni][1] * asv[1] + acc[ni][2] * asv[2] + acc[ni][3] * asv[3];
    pd[ni] = acc[ni][0] * adv[0] + acc[ni][1] * adv[1] + acc[ni][2] * adv[2] + acc[ni][3] * adv[3];
  }
#pragma unroll
  for (int off = CG / 2; off > 0; off >>= 1) {
#pragma unroll
    for (int ni = 0; ni < 4; ++ni) {
      ps[ni] += __shfl_xor(ps[ni], off);
      pd[ni] += __shfl_xor(pd[ni], off);
    }
  }
#pragma unroll
  for (int ni = 0; ni < 4; ++ni) {
    int v = v0 + n0 + ni;
    if (v < n) {
      float4 o = make_float4(acc[ni][0], acc[ni][1], acc[ni][2], acc[ni][3]);
      *(float4*)&h[(size_t)v * C + c0] = o;
      if (cg == 0) { asrc[v] = ps[ni]; adst[v] = pd[ni]; }
    }
  }
}

// ---------------- per-node softmax + aggregate ----------------
// No-max softmax (logits bounded, |lg| < ~4) + deferred normalization:
// attr holds UNNORMALIZED ex of this layer on output; oinv[v] = 1/denom.
// Next layer folds pinv[v] into its per-edge scale (wave-uniform).
// C=64: 1 node per wave. C=32: 2 nodes per wave (half-wave each).
template <int LAYER, int C>
__global__ __launch_bounds__(256) void agg_k(
    const int* __restrict__ rowptr, const int* __restrict__ src_csr,
    const float* __restrict__ h, const float* __restrict__ asrc,
    const float* __restrict__ adst, float* __restrict__ attr,
    const float* __restrict__ pinv, const float* __restrict__ lp1,
    const float* __restrict__ lp2, float* __restrict__ oinv,
    float* __restrict__ ol1, float* __restrict__ ol2,
    const float* __restrict__ sw, const float* __restrict__ bias,
    float* __restrict__ out, int n) {
  constexpr int L = (C == 64) ? 64 : 32;  // lanes per node
  const int lane = threadIdx.x & 63;
  const int ln = lane & (L - 1);
  const int wid = (blockIdx.x * blockDim.x + threadIdx.x) >> 6;
  const int v = (C == 64) ? wid : wid * 2 + (lane >> 5);
  if (v >= n) return;
  const float s = (LAYER == 1) ? 1.f : (LAYER == 2 ? sw[3] : sw[4]);
  const float fac = (LAYER == 1) ? 1.f : pinv[v];
  const float sf = s * fac;
  const int r0 = rowptr[v], r1 = rowptr[v + 1];
  const float av_d = adst[v], av_s = asrc[v];

  // pass A (lane-parallel): ex per edge -> attr; accumulate rawsum & denom
  float rawsum = 0.f, den = 0.f;
  for (int p = r0 + ln; p < r1; p += L) {
    float a = attr[p];
    rawsum += a;
    float lg = asrc[src_csr[p]] + av_d + sf * a;
    float ex = __expf(LRELU(lg));
    attr[p] = ex;
    den += ex;
  }
  __threadfence_block();  // make attr[] writes visible before uniform re-reads
#pragma unroll
  for (int off = L / 2; off > 0; off >>= 1) {
    rawsum += __shfl_xor(rawsum, off);
    den += __shfl_xor(den, off);
  }
  const float base = av_s + av_d;
  float la1 = 0.f, la2 = 0.f, e1 = 0.f, e2 = 0.f;
  if (LAYER >= 2) { la1 = fac * lp1[v]; e1 = __expf(LRELU(base + s * la1)); den += e1; }
  if (LAYER >= 3) { la2 = fac * lp2[v]; e2 = __expf(LRELU(base + s * la2)); den += e2; }
  int dd = (r1 - r0) + (LAYER - 1);
  if (dd < 1) dd = 1;
  float lmean = (fac * rawsum + la1 + la2) / (float)dd;
  float exm = __expf(LRELU(base + s * lmean));
  den += exm;
  float inv = 1.f / (den + 1e-16f);
  if (ln == 0) {
    if (LAYER < 3) oinv[v] = inv;
    if (LAYER == 1) ol1[v] = exm;
    if (LAYER == 2) { ol1[v] = e1; ol2[v] = exm; }
  }

  // pass B (serial over edges, lane = channel, 4-deep ILP)
  const int c = ln;
  const float* __restrict__ hc = h + c;
  float a0 = 0.f, a1 = 0.f, a2 = 0.f, a3 = 0.f;
  int p = r0;
  for (; p + 4 <= r1; p += 4) {
    int s0 = src_csr[p], s1 = src_csr[p + 1], s2 = src_csr[p + 2], s3 = src_csr[p + 3];
    float e0_ = attr[p], e1_ = attr[p + 1], e2_ = attr[p + 2], e3_ = attr[p + 3];
    a0 += e0_ * hc[(size_t)s0 * C];
    a1 += e1_ * hc[(size_t)s1 * C];
    a2 += e2_ * hc[(size_t)s2 * C];
    a3 += e3_ * hc[(size_t)s3 * C];
  }
  for (; p < r1; ++p) a0 += attr[p] * hc[(size_t)src_csr[p] * C];
  float hv = hc[(size_t)v * C];
  float acc = (a0 + a1) + (a2 + a3) + (e1 + e2 + exm) * hv;
  float o = acc * inv + bias[c];
  if (LAYER < 3) o = fmaxf(o, 0.f);
  out[(size_t)v * C + c] = o;
}

// ---------------- global mean pool (block per graph) ----------------

__global__ void pool_k(const float* __restrict__ h, const int* __restrict__ batch,
                       float* __restrict__ out, int n) {
  int g = blockIdx.x;
  int lo = 0, hi = n;
  while (lo < hi) { int m = (lo + hi) >> 1; if (batch[m] < g) lo = m + 1; else hi = m; }
  int start = lo;
  hi = n;
  while (lo < hi) { int m = (lo + hi) >> 1; if (batch[m] < g + 1) lo = m + 1; else hi = m; }
  int end = lo;
  int t = threadIdx.x;
  int c = t & 31, r = t >> 5;
  float acc = 0.f;
  for (int v = start + r; v < end; v += 8) acc += h[(size_t)v * 32 + c];
  __shared__ float s[256];
  s[t] = acc;
  __syncthreads();
  if (t < 128) s[t] += s[t + 128];
  __syncthreads();
  if (t < 64) s[t] += s[t + 64];
  __syncthreads();
  if (t < 32) {
    float tot = s[t] + s[t + 32];
    int cnt = end - start;
    out[g * 32 + t] = tot / (float)(cnt > 0 ? cnt : 1);
  }
}

// ---------------- launch ----------------

extern "C" void kernel_launch(void* const* d_in, const int* in_sizes, int n_in,
                              void* d_out, int out_size, void* d_ws, size_t ws_size,
                              hipStream_t stream) {
  const float* x     = (const float*)d_in[0];
  const int*   ei    = (const int*)d_in[1];
  const float* eattr = (const float*)d_in[2];
  const int*   batch = (const int*)d_in[3];
  const float *W1 = (const float*)d_in[4],  *as1 = (const float*)d_in[5],
              *ad1 = (const float*)d_in[6], *We1 = (const float*)d_in[7],
              *ae1 = (const float*)d_in[8], *b1  = (const float*)d_in[9];
  const float *W2 = (const float*)d_in[10], *as2 = (const float*)d_in[11],
              *ad2 = (const float*)d_in[12], *We2 = (const float*)d_in[13],
              *ae2 = (const float*)d_in[14], *b2  = (const float*)d_in[15];
  const float *W3 = (const float*)d_in[16], *as3 = (const float*)d_in[17],
              *ad3 = (const float*)d_in[18], *We3 = (const float*)d_in[19],
              *ae3 = (const float*)d_in[20], *b3  = (const float*)d_in[21];

  const int n = in_sizes[3];
  const int E = in_sizes[1] / 2;
  const int G = out_size / 32;
  const int* srcp = ei;
  const int* dstp = ei + E;

  char* w = (char*)d_ws;
  auto alloc = [&](size_t bytes) -> void* {
    void* p = (void*)w;
    w += (bytes + 255) & ~(size_t)255;
    return p;
  };
  int*   deg     = (int*)alloc((size_t)n * 4);
  int*   fill    = (int*)alloc((size_t)n * 4);
  int*   rowptr  = (int*)alloc((size_t)(n + 1) * 4);
  int*   bsum    = (int*)alloc(1024);
  int*   boff    = (int*)alloc(1024);
  int*   src_csr = (int*)alloc((size_t)E * 4);
  float* attr    = (float*)alloc((size_t)E * 4);
  float* H       = (float*)alloc((size_t)n * 64 * 4);
  float* O       = (float*)alloc((size_t)n * 64 * 4);
  float* asrcB   = (float*)alloc((size_t)n * 4);
  float* adstB   = (float*)alloc((size_t)n * 4);
  float* loopA   = (float*)alloc((size_t)n * 4);
  float* loopB1  = (float*)alloc((size_t)n * 4);
  float* loopB2  = (float*)alloc((size_t)n * 4);
  float* invA    = (float*)alloc((size_t)n * 4);
  float* invB    = (float*)alloc((size_t)n * 4);
  float* sw      = (float*)alloc(256);

  const int nb = (n + 1023) / 1024;
  dim3 blk256(256);
  dim3 gN((n + 255) / 256);
  dim3 gE((E + 255) / 256);
  dim3 gWave((n + 3) / 4);                 // wave per node
  const int nw3 = (n + 1) / 2;             // 2 nodes per wave (layer 3)
  dim3 gWave3((nw3 + 3) / 4);

  zero_ints_k<<<gN, blk256, 0, stream>>>(deg, fill, n);
  small_weights_k<<<1, 64, 0, stream>>>(We1, ae1, We2, ae2, We3, ae3, sw);
  count_deg_k<<<gE, blk256, 0, stream>>>(dstp, deg, E);
  scan1_k<<<nb, 1024, 0, stream>>>(deg, rowptr, bsum, n);
  scan2_k<<<1, 64, 0, stream>>>(bsum, boff, nb);
  scan3_k<<<gN, blk256, 0, stream>>>(rowptr, boff, n);
  scatter_k<<<gE, blk256, 0, stream>>>(srcp, dstp, eattr, rowptr, fill, src_csr, attr, sw, E);

  // layer 1
  gemm1_k<<<gWave, blk256, 0, stream>>>(x, W1, as1, ad1, H, asrcB, adstB, n);
  agg_k<1, 64><<<gWave, blk256, 0, stream>>>(rowptr, src_csr, H, asrcB, adstB, attr,
                                             nullptr, nullptr, nullptr,
                                             invA, loopA, nullptr, sw, b1, O, n);
  // layer 2
  gemm_tile_k<64><<<dim3((n + 63) / 64), blk256, 0, stream>>>(O, W2, as2, ad2, H, asrcB, adstB, n);
  agg_k<2, 64><<<gWave, blk256, 0, stream>>>(rowptr, src_csr, H, asrcB, adstB, attr,
                                             invA, loopA, nullptr,
                                             invB, loopB1, loopB2, sw, b2, O, n);
  // layer 3
  gemm_tile_k<32><<<dim3((n + 127) / 128), blk256, 0, stream>>>(O, W3, as3, ad3, H, asrcB, adstB, n);
  agg_k<3, 32><<<gWave3, blk256, 0, stream>>>(rowptr, src_csr, H, asrcB, adstB, attr,
                                              invB, loopB1, loopB2,
                                              nullptr, nullptr, nullptr, sw, b3, O, n);
  // pool
  pool_k<<<G, blk256, 0, stream>>>(O, batch, (float*)d_out, n);
}